// Round 19
// baseline (365.813 us; speedup 1.0000x reference)
//
#include <hip/hip_runtime.h>
#include <hip/hip_bf16.h>

// DA block (DANet) — Round 19: k_pbm v5.
//  R18 counters: k_pbm 72us, FETCH 21MB vs ~6MB unique -> cross-XCD L2 thrash
//  (both batches on every XCD: 7MB working set > 4MB L2) + 1 wave/SIMD latency
//  exposure at the per-iter barrier drain.
//  v5: (1) XCD-aware 1D swizzle (XCD=id%8 heuristic): XCDs 0-3 -> b=0, 4-7 -> b=1
//          -> per-XCD working set ~3.5MB fits L2;
//      (2) 2x-unrolled register-double-buffered K/V pipeline: prefetch issued
//          right after the barrier into the alternate frag set (no reg copies)
//          -> issue-to-use distance ~ one full phase (~300cyc) covers L2 latency.
//  Same arithmetic/order -> bit-identical output. k_pam2 gets the same swizzle.
//  All other kernels identical to R18-green. Inputs fp32 dict order; output fp32.

#define B_ 2
#define C_ 256
#define N_ 4096
#define QK_ 32

#define TI_ 32     // i-rows per block (pass A & B)
#define TJ_ 64     // j per tile
#define PP_ 72     // p LDS pitch (bf16) = 144 B

typedef __hip_bfloat16 bf16;
typedef __attribute__((ext_vector_type(8))) short bf16x8f;   // MFMA A/B frag
typedef __attribute__((ext_vector_type(4))) float f32x4;     // MFMA C/D frag

union bf8pack { bf16 h[8]; int4 v; bf16x8f f; };

// ---- k_qk1: partial Q,K projections over a 64-channel chunk ----
__global__ __launch_bounds__(256) void k_qk1(
    const float* __restrict__ x, const float* __restrict__ wq, const float* __restrict__ wk,
    float* __restrict__ qp, float* __restrict__ kp) {
  int b = blockIdx.z;
  int cg = blockIdx.y;                      // 4 chunks of 64 channels
  int n = blockIdx.x * 256 + threadIdx.x;
  float qa[QK_], ka[QK_];
#pragma unroll
  for (int o = 0; o < QK_; o++) { qa[o] = 0.f; ka[o] = 0.f; }
  const float* xp = x + ((size_t)b * C_ + cg * 64) * N_ + n;
  for (int c = 0; c < 64; c++) {
    float xv = xp[(size_t)c * N_];
    int cc = cg * 64 + c;
#pragma unroll
    for (int o = 0; o < QK_; o++) {
      qa[o] += wq[o * C_ + cc] * xv;   // uniform weight loads -> scalar path
      ka[o] += wk[o * C_ + cc] * xv;
    }
  }
  float4* qo = (float4*)(qp + (((size_t)cg * B_ + b) * N_ + n) * QK_);
  float4* ko = (float4*)(kp + (((size_t)cg * B_ + b) * N_ + n) * QK_);
#pragma unroll
  for (int u = 0; u < 8; u++) {
    qo[u] = make_float4(qa[4 * u], qa[4 * u + 1], qa[4 * u + 2], qa[4 * u + 3]);
    ko[u] = make_float4(ka[4 * u], ka[4 * u + 1], ka[4 * u + 2], ka[4 * u + 3]);
  }
}

// ---- k_qk2 v2: combine partials + bias, emit hi/lo bf16 split arrays ----
__global__ __launch_bounds__(256) void k_qk2(
    const float* __restrict__ qp, const float* __restrict__ kp,
    const float* __restrict__ bq, const float* __restrict__ bk,
    bf16* __restrict__ qhi, bf16* __restrict__ qlo,
    bf16* __restrict__ khi, bf16* __restrict__ klo) {
  int t = blockIdx.x * 256 + threadIdx.x;    // b*N + n
  int b = t >> 12, n = t & (N_ - 1);
  float qa[QK_], ka[QK_];
#pragma unroll
  for (int o = 0; o < QK_; o++) { qa[o] = bq[o]; ka[o] = bk[o]; }
#pragma unroll
  for (int cg = 0; cg < 4; cg++) {
    const float4* qs = (const float4*)(qp + (((size_t)cg * B_ + b) * N_ + n) * QK_);
    const float4* ks = (const float4*)(kp + (((size_t)cg * B_ + b) * N_ + n) * QK_);
#pragma unroll
    for (int u = 0; u < 8; u++) {
      float4 q4 = qs[u], k4 = ks[u];
      qa[4 * u] += q4.x; qa[4 * u + 1] += q4.y; qa[4 * u + 2] += q4.z; qa[4 * u + 3] += q4.w;
      ka[4 * u] += k4.x; ka[4 * u + 1] += k4.y; ka[4 * u + 2] += k4.z; ka[4 * u + 3] += k4.w;
    }
  }
  size_t base = (size_t)t * QK_;
#pragma unroll
  for (int g = 0; g < 4; g++) {
    bf8pack qh, ql, kh, kl;
#pragma unroll
    for (int u = 0; u < 8; u++) {
      float qv = qa[g * 8 + u], kv = ka[g * 8 + u];
      bf16 qhh = __float2bfloat16(qv);
      bf16 khh = __float2bfloat16(kv);
      qh.h[u] = qhh; ql.h[u] = __float2bfloat16(qv - __bfloat162float(qhh));
      kh.h[u] = khh; kl.h[u] = __float2bfloat16(kv - __bfloat162float(khh));
    }
    *(int4*)(qhi + base + g * 8) = qh.v;
    *(int4*)(qlo + base + g * 8) = ql.v;
    *(int4*)(khi + base + g * 8) = kh.v;
    *(int4*)(klo + base + g * 8) = kl.v;
  }
}

// ---- k_vbf: V proj -> vbf[b,c,j] bf16; 8 channels/block ----
__global__ __launch_bounds__(256) void k_vbf(
    const float* __restrict__ x, const float* __restrict__ wv, const float* __restrict__ bv,
    bf16* __restrict__ vbf) {
  int b = blockIdx.z;
  int co0 = blockIdx.y * 8;
  int n0 = blockIdx.x * 256;
  int tid = threadIdx.x;
  float acc[8];
#pragma unroll
  for (int o = 0; o < 8; o++) acc[o] = bv[co0 + o];
  const float* xp = x + (size_t)b * C_ * N_ + n0 + tid;
  for (int c = 0; c < C_; c++) {
    float xv = xp[(size_t)c * N_];
#pragma unroll
    for (int o = 0; o < 8; o++) acc[o] += wv[(co0 + o) * C_ + c] * xv;
  }
#pragma unroll
  for (int o = 0; o < 8; o++)
    vbf[((size_t)b * C_ + co0 + o) * N_ + n0 + tid] = __float2bfloat16(acc[o]);
}

// ---- k_pam2 v3: MFMA pass A — direct-global frags + XCD-aware swizzle ----
__global__ __launch_bounds__(256) void k_pam2(
    const bf16* __restrict__ qhi, const bf16* __restrict__ qlo,
    const bf16* __restrict__ khi, const bf16* __restrict__ klo,
    float* __restrict__ mrow, float* __restrict__ lrowi) {
  int id = blockIdx.x;                 // 256 blocks, 1D
  int xcd = id & 7;
  int b = xcd >> 2;                    // XCDs 0-3 -> b0, 4-7 -> b1
  int i0 = (((xcd & 3) << 5) | (id >> 3)) * TI_;
  int tid = threadIdx.x;
  int lane = tid & 63, wave = tid >> 6;
  int n16 = lane & 15, quad = lane >> 4;

  __shared__ float red_m[4 * 32], red_l[4 * 32];

  bf16x8f ahf[2], alf[2];
#pragma unroll
  for (int ih = 0; ih < 2; ih++) {
    size_t qoff = ((size_t)b * N_ + i0 + ih * 16 + n16) * QK_ + quad * 8;
    ahf[ih] = *(const bf16x8f*)(const void*)(qhi + qoff);
    alf[ih] = *(const bf16x8f*)(const void*)(qlo + qoff);
  }

  float m8[8], l8[8];
#pragma unroll
  for (int k = 0; k < 8; k++) { m8[k] = -3.0e38f; l8[k] = 0.f; }

  const bf16* khb = khi + ((size_t)b * N_ + wave * 16 + n16) * QK_ + quad * 8;
  const bf16* klb = klo + ((size_t)b * N_ + wave * 16 + n16) * QK_ + quad * 8;
  bf16x8f khf = *(const bf16x8f*)(const void*)khb;
  bf16x8f klf = *(const bf16x8f*)(const void*)klb;

  for (int jt = 0; jt < N_ / TJ_; jt++) {
    bf16x8f khn, kln;
    if (jt + 1 < N_ / TJ_) {
      size_t off = (size_t)(jt + 1) * TJ_ * QK_;
      khn = *(const bf16x8f*)(const void*)(khb + off);
      kln = *(const bf16x8f*)(const void*)(klb + off);
    }
#pragma unroll
    for (int ih = 0; ih < 2; ih++) {
      f32x4 z = (f32x4)(0.f);
      z = __builtin_amdgcn_mfma_f32_16x16x32_bf16(ahf[ih], khf, z, 0, 0, 0);
      z = __builtin_amdgcn_mfma_f32_16x16x32_bf16(alf[ih], khf, z, 0, 0, 0);
      z = __builtin_amdgcn_mfma_f32_16x16x32_bf16(ahf[ih], klf, z, 0, 0, 0);
#pragma unroll
      for (int r = 0; r < 4; r++) {
        int k = ih * 4 + r;
        float sv = z[r];
        float nm = fmaxf(m8[k], sv);
        l8[k] = l8[k] * __expf(m8[k] - nm) + __expf(sv - nm);
        m8[k] = nm;
      }
    }
    khf = khn; klf = kln;
  }
#pragma unroll
  for (int d = 1; d < 16; d <<= 1) {
#pragma unroll
    for (int k = 0; k < 8; k++) {
      float om = __shfl_xor(m8[k], d, 64);
      float ol = __shfl_xor(l8[k], d, 64);
      float nm = fmaxf(m8[k], om);
      l8[k] = l8[k] * __expf(m8[k] - nm) + ol * __expf(om - nm);
      m8[k] = nm;
    }
  }
  if (n16 == 0) {
#pragma unroll
    for (int ih = 0; ih < 2; ih++)
#pragma unroll
      for (int r = 0; r < 4; r++) {
        int i = ih * 16 + quad * 4 + r;
        red_m[wave * 32 + i] = m8[ih * 4 + r];
        red_l[wave * 32 + i] = l8[ih * 4 + r];
      }
  }
  __syncthreads();
  if (tid < 32) {
    float wm[4];
    float M = -3.0e38f;
#pragma unroll
    for (int w = 0; w < 4; w++) { wm[w] = red_m[w * 32 + tid]; M = fmaxf(M, wm[w]); }
    float L = 0.f;
#pragma unroll
    for (int w = 0; w < 4; w++) L += red_l[w * 32 + tid] * __expf(wm[w] - M);
    mrow[b * N_ + i0 + tid] = M;
    lrowi[b * N_ + i0 + tid] = 1.0f / L;
  }
}

// ---- k_pbm v5: XCD-swizzled, 2x-unrolled register-double-buffered pipeline ----
__global__ __launch_bounds__(256) void k_pbm(
    const bf16* __restrict__ qhi, const bf16* __restrict__ qlo,
    const bf16* __restrict__ khi, const bf16* __restrict__ klo,
    const bf16* __restrict__ vbf,
    const float* __restrict__ mrow, const float* __restrict__ lrowi,
    float* __restrict__ pamT) {
  int id = blockIdx.x;                 // 256 blocks, 1D
  int xcd = id & 7;
  int b = xcd >> 2;                    // XCDs 0-3 -> b0, 4-7 -> b1
  int i0 = (((xcd & 3) << 5) | (id >> 3)) * TI_;
  int tid = threadIdx.x;
  int lane = tid & 63, wave = tid >> 6;
  int n16 = lane & 15, quad = lane >> 4;

  __shared__ __align__(16) bf16 p_s[2][32 * PP_];   // double-buffered (cross-wave)

  float mreg[8], lireg[8];
#pragma unroll
  for (int ih = 0; ih < 2; ih++)
#pragma unroll
    for (int r = 0; r < 4; r++) {
      int i = ih * 16 + quad * 4 + r;
      mreg[ih * 4 + r] = mrow[b * N_ + i0 + i];
      lireg[ih * 4 + r] = lrowi[b * N_ + i0 + i];
    }

  bf16x8f ahf[2], alf[2];
#pragma unroll
  for (int ih = 0; ih < 2; ih++) {
    size_t qoff = ((size_t)b * N_ + i0 + ih * 16 + n16) * QK_ + quad * 8;
    ahf[ih] = *(const bf16x8f*)(const void*)(qhi + qoff);
    alf[ih] = *(const bf16x8f*)(const void*)(qlo + qoff);
  }

  f32x4 acc[2][4];
#pragma unroll
  for (int ih = 0; ih < 2; ih++)
#pragma unroll
    for (int cb = 0; cb < 4; cb++) acc[ih][cb] = (f32x4)(0.f);

  const bf16* khb = khi + ((size_t)b * N_ + wave * 16 + n16) * QK_ + quad * 8;
  const bf16* klb = klo + ((size_t)b * N_ + wave * 16 + n16) * QK_ + quad * 8;
  const bf16* vb0 = vbf + ((size_t)b * C_ + wave * 64 + n16) * N_ + quad * 8;

  bf16x8f kh[2], kl[2], vf[2][4][2];
  // preload set 0 = tile 0
  kh[0] = *(const bf16x8f*)(const void*)khb;
  kl[0] = *(const bf16x8f*)(const void*)klb;
#pragma unroll
  for (int cb = 0; cb < 4; cb++)
#pragma unroll
    for (int h = 0; h < 2; h++)
      vf[0][cb][h] = *(const bf16x8f*)(const void*)(vb0 + (size_t)cb * 16 * N_ + h * 32);

  for (int jt = 0; jt < N_ / TJ_; jt += 2) {
    // ===== phase 0: tile jt (set 0); prefetch tile jt+1 into set 1 =====
    {
      f32x4 s[2];
#pragma unroll
      for (int ih = 0; ih < 2; ih++) {
        f32x4 z = (f32x4)(0.f);
        z = __builtin_amdgcn_mfma_f32_16x16x32_bf16(ahf[ih], kh[0], z, 0, 0, 0);
        z = __builtin_amdgcn_mfma_f32_16x16x32_bf16(alf[ih], kh[0], z, 0, 0, 0);
        z = __builtin_amdgcn_mfma_f32_16x16x32_bf16(ahf[ih], kl[0], z, 0, 0, 0);
        s[ih] = z;
      }
      bf16* pbuf = p_s[0];
#pragma unroll
      for (int ih = 0; ih < 2; ih++)
#pragma unroll
        for (int r = 0; r < 4; r++) {
          int i = ih * 16 + quad * 4 + r;
          float p = __expf(s[ih][r] - mreg[ih * 4 + r]) * lireg[ih * 4 + r];
          pbuf[i * PP_ + wave * 16 + n16] = __float2bfloat16(p);
        }
      __syncthreads();   // P(jt) visible
      // prefetch tile jt+1 into set 1 (always valid: jt+1 <= 63)
      {
        size_t koff = (size_t)(jt + 1) * TJ_ * QK_;
        kh[1] = *(const bf16x8f*)(const void*)(khb + koff);
        kl[1] = *(const bf16x8f*)(const void*)(klb + koff);
        int jb = (jt + 1) * TJ_;
#pragma unroll
        for (int cb = 0; cb < 4; cb++)
#pragma unroll
          for (int h = 0; h < 2; h++)
            vf[1][cb][h] = *(const bf16x8f*)(const void*)(vb0 + (size_t)cb * 16 * N_ + jb + h * 32);
      }
      bf16x8f pa0[2], pa1[2];
#pragma unroll
      for (int ih = 0; ih < 2; ih++) {
        pa0[ih] = *(const bf16x8f*)(const void*)(pbuf + (ih * 16 + n16) * PP_ + quad * 8);
        pa1[ih] = *(const bf16x8f*)(const void*)(pbuf + (ih * 16 + n16) * PP_ + 32 + quad * 8);
      }
#pragma unroll
      for (int ih = 0; ih < 2; ih++)
#pragma unroll
        for (int cb = 0; cb < 4; cb++) {
          acc[ih][cb] = __builtin_amdgcn_mfma_f32_16x16x32_bf16(pa0[ih], vf[0][cb][0], acc[ih][cb], 0, 0, 0);
          acc[ih][cb] = __builtin_amdgcn_mfma_f32_16x16x32_bf16(pa1[ih], vf[0][cb][1], acc[ih][cb], 0, 0, 0);
        }
    }
    // ===== phase 1: tile jt+1 (set 1); prefetch tile jt+2 into set 0 =====
    {
      f32x4 s[2];
#pragma unroll
      for (int ih = 0; ih < 2; ih++) {
        f32x4 z = (f32x4)(0.f);
        z = __builtin_amdgcn_mfma_f32_16x16x32_bf16(ahf[ih], kh[1], z, 0, 0, 0);
        z = __builtin_amdgcn_mfma_f32_16x16x32_bf16(alf[ih], kh[1], z, 0, 0, 0);
        z = __builtin_amdgcn_mfma_f32_16x16x32_bf16(ahf[ih], kl[1], z, 0, 0, 0);
        s[ih] = z;
      }
      bf16* pbuf = p_s[1];
#pragma unroll
      for (int ih = 0; ih < 2; ih++)
#pragma unroll
        for (int r = 0; r < 4; r++) {
          int i = ih * 16 + quad * 4 + r;
          float p = __expf(s[ih][r] - mreg[ih * 4 + r]) * lireg[ih * 4 + r];
          pbuf[i * PP_ + wave * 16 + n16] = __float2bfloat16(p);
        }
      __syncthreads();   // P(jt+1) visible
      if (jt + 2 < N_ / TJ_) {
        size_t koff = (size_t)(jt + 2) * TJ_ * QK_;
        kh[0] = *(const bf16x8f*)(const void*)(khb + koff);
        kl[0] = *(const bf16x8f*)(const void*)(klb + koff);
        int jb = (jt + 2) * TJ_;
#pragma unroll
        for (int cb = 0; cb < 4; cb++)
#pragma unroll
          for (int h = 0; h < 2; h++)
            vf[0][cb][h] = *(const bf16x8f*)(const void*)(vb0 + (size_t)cb * 16 * N_ + jb + h * 32);
      }
      bf16x8f pa0[2], pa1[2];
#pragma unroll
      for (int ih = 0; ih < 2; ih++) {
        pa0[ih] = *(const bf16x8f*)(const void*)(pbuf + (ih * 16 + n16) * PP_ + quad * 8);
        pa1[ih] = *(const bf16x8f*)(const void*)(pbuf + (ih * 16 + n16) * PP_ + 32 + quad * 8);
      }
#pragma unroll
      for (int ih = 0; ih < 2; ih++)
#pragma unroll
        for (int cb = 0; cb < 4; cb++) {
          acc[ih][cb] = __builtin_amdgcn_mfma_f32_16x16x32_bf16(pa0[ih], vf[1][cb][0], acc[ih][cb], 0, 0, 0);
          acc[ih][cb] = __builtin_amdgcn_mfma_f32_16x16x32_bf16(pa1[ih], vf[1][cb][1], acc[ih][cb], 0, 0, 0);
        }
    }
  }
  // epilogue: C/D layout col=lane&15, row=quad*4+r; c = wave*64+cb*16+n16
#pragma unroll
  for (int ih = 0; ih < 2; ih++)
#pragma unroll
    for (int cb = 0; cb < 4; cb++) {
      int c = wave * 64 + cb * 16 + n16;
#pragma unroll
      for (int r = 0; r < 4; r++) {
        int i = ih * 16 + quad * 4 + r;
        pamT[((size_t)b * N_ + i0 + i) * C_ + c] = acc[ih][cb][r];
      }
    }
}

// ---- k_ce: CAM energy partials over K-chunks ----
__global__ __launch_bounds__(256) void k_ce(const float* __restrict__ x, float* __restrict__ eCp) {
  int b = blockIdx.z;
  int kc = blockIdx.y;
  int it = blockIdx.x & 7, jt = blockIdx.x >> 3;
  int i0 = it * 32, j0 = jt * 32;
  __shared__ float xi[32 * 65], xj[32 * 65];
  int tid = threadIdx.x;
  int ti2 = (tid & 15) * 2, tj2 = (tid >> 4) * 2;
  float a00 = 0.f, a01 = 0.f, a10 = 0.f, a11 = 0.f;
  for (int n0 = 0; n0 < 512; n0 += 64) {
    __syncthreads();
#pragma unroll
    for (int k = 0; k < 8; k++) {
      int e = k * 256 + tid;
      int r = e >> 6, c = e & 63;
      xi[r * 65 + c] = x[((size_t)b * C_ + i0 + r) * N_ + kc * 512 + n0 + c];
      xj[r * 65 + c] = x[((size_t)b * C_ + j0 + r) * N_ + kc * 512 + n0 + c];
    }
    __syncthreads();
#pragma unroll 4
    for (int n = 0; n < 64; n++) {
      float u0 = xi[ti2 * 65 + n], u1 = xi[(ti2 + 1) * 65 + n];
      float w0 = xj[tj2 * 65 + n], w1 = xj[(tj2 + 1) * 65 + n];
      a00 += u0 * w0; a01 += u0 * w1; a10 += u1 * w0; a11 += u1 * w1;
    }
  }
  float* dst = eCp + (((size_t)kc * B_ + b) * C_ + i0) * C_ + j0;
  dst[(ti2 + 0) * C_ + tj2 + 0] = a00;
  dst[(ti2 + 0) * C_ + tj2 + 1] = a01;
  dst[(ti2 + 1) * C_ + tj2 + 0] = a10;
  dst[(ti2 + 1) * C_ + tj2 + 1] = a11;
}

// ---- k_cs: CAM softmax over -e ----
__global__ __launch_bounds__(256) void k_cs(const float* __restrict__ eCp, float* __restrict__ attnC) {
  int row = blockIdx.x;
  int b = row >> 8, i = row & 255;
  int j = threadIdx.x;
  float e = 0.f;
#pragma unroll
  for (int kc = 0; kc < 8; kc++) e += eCp[(((size_t)kc * B_ + b) * C_ + i) * C_ + j];
  float ne = -e;
  __shared__ float buf[256];
  buf[j] = ne;
  __syncthreads();
  for (int st = 128; st >= 1; st >>= 1) {
    if (j < st) buf[j] = fmaxf(buf[j], buf[j + st]);
    __syncthreads();
  }
  float m = buf[0];
  __syncthreads();
  float p = __expf(ne - m);
  buf[j] = p;
  __syncthreads();
  for (int st = 128; st >= 1; st >>= 1) {
    if (j < st) buf[j] += buf[j + st];
    __syncthreads();
  }
  attnC[(size_t)row * C_ + j] = p / buf[0];
}

// ---- k_co v2: CAM out + combine; 16 ch/block, j-unroll x8 hoisted loads ----
__global__ __launch_bounds__(256) void k_co(
    const float* __restrict__ x, const float* __restrict__ attnC, const float* __restrict__ pamT,
    const float* __restrict__ gpam, const float* __restrict__ gcam, float* __restrict__ out) {
  int b = blockIdx.z, c0 = blockIdx.y * 16, n0 = blockIdx.x * 256;
  int tid = threadIdx.x;
  __shared__ float pam_s[256 * 17];
#pragma unroll
  for (int k = 0; k < 16; k++) {
    int e = k * 256 + tid;
    int r = e >> 4, cc = e & 15;
    pam_s[r * 17 + cc] = pamT[((size_t)b * N_ + n0 + r) * C_ + c0 + cc];
  }
  __syncthreads();
  float acc[16];
#pragma unroll
  for (int i = 0; i < 16; i++) acc[i] = 0.f;
  const float* arow = attnC + ((size_t)b * C_ + c0) * C_;
  for (int j0 = 0; j0 < C_; j0 += 8) {
    float xv[8];
#pragma unroll
    for (int u = 0; u < 8; u++)          // 8 independent loads in flight
      xv[u] = x[((size_t)b * C_ + j0 + u) * N_ + n0 + tid];
#pragma unroll
    for (int i = 0; i < 16; i++)
#pragma unroll
      for (int u = 0; u < 8; u++)        // ascending j per acc[i] -> same order
        acc[i] += arow[i * C_ + j0 + u] * xv[u];
  }
  float gp = gpam[0], gc = gcam[0];
#pragma unroll
  for (int i = 0; i < 16; i++) {
    size_t idx = ((size_t)b * C_ + c0 + i) * N_ + n0 + tid;
    out[idx] = gp * pam_s[tid * 17 + i] + gc * acc[i] + 2.0f * x[idx];
  }
}

extern "C" void kernel_launch(void* const* d_in, const int* in_sizes, int n_in,
                              void* d_out, int out_size, void* d_ws, size_t ws_size,
                              hipStream_t stream) {
  const float* x  = (const float*)d_in[0];
  const float* wq = (const float*)d_in[1];
  const float* bq = (const float*)d_in[2];
  const float* wk = (const float*)d_in[3];
  const float* bk = (const float*)d_in[4];
  const float* wv = (const float*)d_in[5];
  const float* bv = (const float*)d_in[6];
  const float* gp = (const float*)d_in[7];
  const float* gc = (const float*)d_in[8];
  float* out = (float*)d_out;

  float* ws = (float*)d_ws;
  size_t o = 0;
  float* pamT  = ws + o; o += (size_t)B_ * N_ * C_;     // 2097152
  float* mrow  = ws + o; o += (size_t)B_ * N_;          // 8192
  float* lrowi = ws + o; o += (size_t)B_ * N_;          // 8192
  float* eCp   = ws + o; o += (size_t)8 * B_ * C_ * C_; // 1048576
  float* attnC = ws + o; o += (size_t)B_ * C_ * C_;     // 131072
  bf16*  vbf   = (bf16*)(ws + o); o += (size_t)B_ * N_ * C_ / 2;   // 1048576
  bf16*  qhi   = (bf16*)(ws + o); o += (size_t)B_ * N_ * QK_ / 2;  // 131072
  bf16*  qlo   = (bf16*)(ws + o); o += (size_t)B_ * N_ * QK_ / 2;  // 131072
  bf16*  khi   = (bf16*)(ws + o); o += (size_t)B_ * N_ * QK_ / 2;  // 131072
  bf16*  klo   = (bf16*)(ws + o); o += (size_t)B_ * N_ * QK_ / 2;  // 131072
  float* qpprt = ws + o; o += (size_t)4 * B_ * N_ * QK_; // 1048576
  float* kpprt = ws + o; o += (size_t)4 * B_ * N_ * QK_; // 1048576
  // total ~6.8 M floats = 27.3 MB

  k_qk1<<<dim3(16, 4, B_), dim3(256), 0, stream>>>(x, wq, wk, qpprt, kpprt);
  k_qk2<<<dim3(32), dim3(256), 0, stream>>>(qpprt, kpprt, bq, bk, qhi, qlo, khi, klo);
  k_vbf<<<dim3(16, 32, B_), dim3(256), 0, stream>>>(x, wv, bv, vbf);
  k_pam2<<<dim3(256), dim3(256), 0, stream>>>(qhi, qlo, khi, klo, mrow, lrowi);
  k_pbm<<<dim3(256), dim3(256), 0, stream>>>(qhi, qlo, khi, klo, vbf, mrow, lrowi, pamT);
  k_ce<<<dim3(64, 8, B_), dim3(256), 0, stream>>>(x, eCp);
  k_cs<<<dim3(B_ * C_), dim3(256), 0, stream>>>(eCp, attnC);
  k_co<<<dim3(16, 16, B_), dim3(256), 0, stream>>>(x, attnC, pamT, gp, gc, out);
}